// Round 1
// baseline (502.321 us; speedup 1.0000x reference)
//
#include <hip/hip_runtime.h>

#define NN 50000
#define NE 800000
#define DD 64
#define NG 64

// ---------------- degree / normalization ----------------
__global__ void fill_deg(float* __restrict__ deg, int n) {
    int i = blockIdx.x * blockDim.x + threadIdx.x;
    if (i < n) deg[i] = 1.0f;  // self-loop weight
}

__global__ void accum_deg(const int* __restrict__ ei, const float* __restrict__ ew,
                          float* __restrict__ deg, int E) {
    int e = blockIdx.x * blockDim.x + threadIdx.x;
    if (e < E) unsafeAtomicAdd(&deg[ei[E + e]], ew[e]);  // deg[col] += w
}

__global__ void make_dis(float* __restrict__ deg, int n) {
    int i = blockIdx.x * blockDim.x + threadIdx.x;
    if (i < n) {
        float d = deg[i];
        deg[i] = d > 0.0f ? rsqrtf(d) : 0.0f;  // in-place: deg -> dis
    }
}

// ---------------- GEMM: xw = act(X) @ W ; A = xw ; B = xw * dis^2 ----------------
// ACT: apply relu(v + bias_prev[k]) to input rows (layer-2 path). For layer 2,
// X and B alias the same buffer: rows are staged in LDS before being overwritten,
// and each row belongs to exactly one block.
template<bool ACT>
__global__ __launch_bounds__(256) void gemm_init(
    const float* __restrict__ X, const float* __restrict__ W,
    const float* __restrict__ bias_prev, const float* __restrict__ dis,
    float* __restrict__ A, float* __restrict__ B)
{
    __shared__ float Ws[64][64];
    __shared__ float Xs[16][64];
    const int t = threadIdx.x;
    const int row0 = blockIdx.x * 16;

    // stage W (16 KB)
    #pragma unroll
    for (int s = t; s < 64 * 64; s += 256) Ws[s >> 6][s & 63] = W[s];
    // stage 16 input rows, activation fused on read
    #pragma unroll
    for (int s = t; s < 16 * 64; s += 256) {
        int rr = s >> 6, k = s & 63;
        float v = X[(row0 + rr) * DD + k];
        if (ACT) v = fmaxf(v + bias_prev[k], 0.0f);
        Xs[rr][k] = v;
    }
    __syncthreads();

    const int j = t & 63;
    const int r0 = t >> 6;
    #pragma unroll
    for (int rr = r0; rr < 16; rr += 4) {
        float acc = 0.0f;
        #pragma unroll
        for (int k = 0; k < 64; ++k) acc += Xs[rr][k] * Ws[k][j];
        int gi = row0 + rr;
        float di = dis[gi];
        A[gi * DD + j] = acc;
        B[gi * DD + j] = acc * di * di;  // self-loop init
    }
}

// ---------------- edge scatter: B[c] += A[r] * (dis[r]*w*dis[c]) ----------------
__global__ __launch_bounds__(256) void scatter_edges(
    const int* __restrict__ ei, const float* __restrict__ ew,
    const float* __restrict__ dis,
    const float* __restrict__ A, float* __restrict__ B, int E)
{
    int e = blockIdx.x * 4 + (threadIdx.x >> 6);
    int lane = threadIdx.x & 63;
    if (e < E) {
        int r = ei[e], c = ei[E + e];
        float norm = dis[r] * ew[e] * dis[c];
        unsafeAtomicAdd(&B[c * DD + lane], A[r * DD + lane] * norm);
    }
}

// ---------------- pooling ----------------
__global__ void zero_small(float* __restrict__ p, int n) {
    int i = blockIdx.x * blockDim.x + threadIdx.x;
    if (i < n) p[i] = 0.0f;
}

__global__ __launch_bounds__(64) void pool(
    const float* __restrict__ B, const float* __restrict__ b2,
    const int* __restrict__ batch,
    float* __restrict__ sums, float* __restrict__ cnts, int n)
{
    const int lane = threadIdx.x;
    const int start = blockIdx.x * 128;
    const int end = min(start + 128, n);
    const float bb = b2[lane];
    float acc = 0.0f;
    int cn = 0;
    int curg = batch[start];
    for (int i = start; i < end; ++i) {
        int g = batch[i];
        if (g != curg) {
            unsafeAtomicAdd(&sums[curg * DD + lane], acc);
            if (lane == 0) unsafeAtomicAdd(&cnts[curg], (float)cn);
            acc = 0.0f; cn = 0; curg = g;
        }
        acc += fmaxf(B[i * DD + lane] + bb, 0.0f);
        cn++;
    }
    if (cn > 0) {
        unsafeAtomicAdd(&sums[curg * DD + lane], acc);
        if (lane == 0) unsafeAtomicAdd(&cnts[curg], (float)cn);
    }
}

__global__ void finalize(const float* __restrict__ sums, const float* __restrict__ cnts,
                         float* __restrict__ out) {
    int i = blockIdx.x * blockDim.x + threadIdx.x;
    if (i < NG * DD) {
        int g = i >> 6;
        out[i] = sums[i] / fmaxf(cnts[g], 1.0f);
    }
}

// ---------------- host ----------------
extern "C" void kernel_launch(void* const* d_in, const int* in_sizes, int n_in,
                              void* d_out, int out_size, void* d_ws, size_t ws_size,
                              hipStream_t stream) {
    const float* x   = (const float*)d_in[0];  // [NN, DD]
    const int*   ei  = (const int*)  d_in[1];  // [2, NE]
    const float* ew  = (const float*)d_in[2];  // [NE]
    const int*   bat = (const int*)  d_in[3];  // [NN]
    const float* W1  = (const float*)d_in[4];
    const float* b1  = (const float*)d_in[5];
    const float* W2  = (const float*)d_in[6];
    const float* b2  = (const float*)d_in[7];
    float* out = (float*)d_out;

    char* ws = (char*)d_ws;
    float* A    = (float*)(ws);                         // [NN*DD] 12.8 MB
    float* B    = (float*)(ws + (size_t)NN * DD * 4);   // [NN*DD] 12.8 MB
    float* dis  = (float*)(ws + (size_t)2 * NN * DD * 4);       // [NN]
    float* sums = (float*)(ws + (size_t)2 * NN * DD * 4 + NN * 4);   // [NG*DD]
    float* cnts = (float*)(ws + (size_t)2 * NN * DD * 4 + NN * 4 + NG * DD * 4);  // [NG]

    // normalization (shared by both layers)
    fill_deg<<<(NN + 255) / 256, 256, 0, stream>>>(dis, NN);
    accum_deg<<<(NE + 255) / 256, 256, 0, stream>>>(ei, ew, dis, NE);
    make_dis<<<(NN + 255) / 256, 256, 0, stream>>>(dis, NN);

    // layer 1
    gemm_init<false><<<NN / 16, 256, 0, stream>>>(x, W1, nullptr, dis, A, B);
    scatter_edges<<<(NE + 3) / 4, 256, 0, stream>>>(ei, ew, dis, A, B, NE);

    // layer 2 (reads B with relu(.+b1), overwrites B with self-loop init)
    gemm_init<true><<<NN / 16, 256, 0, stream>>>(B, W2, b1, dis, A, B);
    scatter_edges<<<(NE + 3) / 4, 256, 0, stream>>>(ei, ew, dis, A, B, NE);

    // pooling (bias+relu fused on read)
    zero_small<<<(NG * DD + NG + 255) / 256, 256, 0, stream>>>(sums, NG * DD + NG);
    pool<<<(NN + 127) / 128, 64, 0, stream>>>(B, b2, bat, sums, cnts, NN);
    finalize<<<(NG * DD + 255) / 256, 256, 0, stream>>>(sums, cnts, out);
}

// Round 2
// 445.293 us; speedup vs baseline: 1.1281x; 1.1281x over previous
//
#include <hip/hip_runtime.h>

#define NN 50000
#define NE 800000
#define DD 64
#define NG 64

// ---------------- init: deg=1 (self loop), counters = 0 ----------------
__global__ void init_k(float* __restrict__ deg, int* __restrict__ cnt,
                       float* __restrict__ sums, float* __restrict__ cnts) {
    int i = blockIdx.x * blockDim.x + threadIdx.x;
    if (i < NN) { deg[i] = 1.0f; cnt[i] = 0; }
    if (i < NG * DD) sums[i] = 0.0f;
    if (i < NG) cnts[i] = 0.0f;
}

// ---------------- histogram by dst + weighted degree ----------------
__global__ void hist_deg(const int* __restrict__ ei, const float* __restrict__ ew,
                         float* __restrict__ deg, int* __restrict__ cnt, int E) {
    int e = blockIdx.x * blockDim.x + threadIdx.x;
    if (e < E) {
        int c = ei[E + e];
        atomicAdd(&cnt[c], 1);
        unsafeAtomicAdd(&deg[c], ew[e]);
    }
}

__global__ void make_dis(float* __restrict__ deg, int n) {
    int i = blockIdx.x * blockDim.x + threadIdx.x;
    if (i < n) {
        float d = deg[i];
        deg[i] = d > 0.0f ? rsqrtf(d) : 0.0f;  // in-place: deg -> dis
    }
}

// ---------------- exclusive scan of cnt -> rowptr, pos (single block) ----------------
__global__ __launch_bounds__(1024) void scan_k(const int* __restrict__ cnt,
                                               int* __restrict__ rowptr,
                                               int* __restrict__ pos) {
    __shared__ int part[1024];
    const int t = threadIdx.x;
    const int CH = 49;  // 1024*49 = 50176 >= NN
    const int base = t * CH;
    int s = 0;
    for (int i = 0; i < CH; ++i) {
        int idx = base + i;
        if (idx < NN) s += cnt[idx];
    }
    part[t] = s;
    __syncthreads();
    for (int off = 1; off < 1024; off <<= 1) {
        int v = (t >= off) ? part[t - off] : 0;
        __syncthreads();
        part[t] += v;
        __syncthreads();
    }
    int run = part[t] - s;  // exclusive base for this chunk
    for (int i = 0; i < CH; ++i) {
        int idx = base + i;
        if (idx < NN) {
            rowptr[idx] = run;
            pos[idx] = run;
            run += cnt[idx];
        }
    }
    if (t == 1023) rowptr[NN] = run;  // == NE
}

// ---------------- place edges sorted by dst, with precomputed norm ----------------
__global__ void place_k(const int* __restrict__ ei, const float* __restrict__ ew,
                        const float* __restrict__ dis, int* __restrict__ pos,
                        int2* __restrict__ srt, int E) {
    int e = blockIdx.x * blockDim.x + threadIdx.x;
    if (e < E) {
        int r = ei[e], c = ei[E + e];
        float w = dis[r] * ew[e] * dis[c];
        int p = atomicAdd(&pos[c], 1);
        srt[p] = make_int2(r, __float_as_int(w));
    }
}

// ---------------- GEMM: A = act(X) @ W ----------------
template<bool ACT>
__global__ __launch_bounds__(256) void gemm_k(
    const float* __restrict__ X, const float* __restrict__ W,
    const float* __restrict__ bias_prev, float* __restrict__ A)
{
    __shared__ float Ws[64][64];
    __shared__ float Xs[16][64];
    const int t = threadIdx.x;
    const int row0 = blockIdx.x * 16;

    #pragma unroll
    for (int s = t; s < 64 * 64; s += 256) Ws[s >> 6][s & 63] = W[s];
    #pragma unroll
    for (int s = t; s < 16 * 64; s += 256) {
        int rr = s >> 6, k = s & 63;
        float v = X[(size_t)(row0 + rr) * DD + k];
        if (ACT) v = fmaxf(v + bias_prev[k], 0.0f);
        Xs[rr][k] = v;
    }
    __syncthreads();

    const int j = t & 63;
    const int r0 = t >> 6;
    #pragma unroll
    for (int rr = r0; rr < 16; rr += 4) {
        float acc = 0.0f;
        #pragma unroll
        for (int k = 0; k < 64; ++k) acc += Xs[rr][k] * Ws[k][j];
        A[(size_t)(row0 + rr) * DD + j] = acc;
    }
}

// ---------------- gather: B[c] = A[c]*dis[c]^2 + sum_e A[r]*norm ----------------
__global__ __launch_bounds__(256) void gather_k(
    const int* __restrict__ rowptr, const int2* __restrict__ srt,
    const float* __restrict__ dis,
    const float* __restrict__ A, float* __restrict__ B)
{
    const int node = blockIdx.x * 4 + (threadIdx.x >> 6);
    const int lane = threadIdx.x & 63;
    if (node >= NN) return;
    const float di = dis[node];
    float acc = A[(size_t)node * DD + lane] * di * di;
    int e = rowptr[node];
    const int end = rowptr[node + 1];
    for (; e + 1 < end; e += 2) {
        int2 p0 = srt[e], p1 = srt[e + 1];
        float a0 = A[(size_t)p0.x * DD + lane];
        float a1 = A[(size_t)p1.x * DD + lane];
        acc += a0 * __int_as_float(p0.y);
        acc += a1 * __int_as_float(p1.y);
    }
    if (e < end) {
        int2 p0 = srt[e];
        acc += A[(size_t)p0.x * DD + lane] * __int_as_float(p0.y);
    }
    B[(size_t)node * DD + lane] = acc;
}

// ---------------- pooling ----------------
__global__ __launch_bounds__(64) void pool(
    const float* __restrict__ B, const float* __restrict__ b2,
    const int* __restrict__ batch,
    float* __restrict__ sums, float* __restrict__ cnts, int n)
{
    const int lane = threadIdx.x;
    const int start = blockIdx.x * 128;
    const int end = min(start + 128, n);
    const float bb = b2[lane];
    float acc = 0.0f;
    int cn = 0;
    int curg = batch[start];
    for (int i = start; i < end; ++i) {
        int g = batch[i];
        if (g != curg) {
            unsafeAtomicAdd(&sums[curg * DD + lane], acc);
            if (lane == 0) unsafeAtomicAdd(&cnts[curg], (float)cn);
            acc = 0.0f; cn = 0; curg = g;
        }
        acc += fmaxf(B[(size_t)i * DD + lane] + bb, 0.0f);
        cn++;
    }
    if (cn > 0) {
        unsafeAtomicAdd(&sums[curg * DD + lane], acc);
        if (lane == 0) unsafeAtomicAdd(&cnts[curg], (float)cn);
    }
}

__global__ void finalize(const float* __restrict__ sums, const float* __restrict__ cnts,
                         float* __restrict__ out) {
    int i = blockIdx.x * blockDim.x + threadIdx.x;
    if (i < NG * DD) {
        int g = i >> 6;
        out[i] = sums[i] / fmaxf(cnts[g], 1.0f);
    }
}

// ---------------- host ----------------
extern "C" void kernel_launch(void* const* d_in, const int* in_sizes, int n_in,
                              void* d_out, int out_size, void* d_ws, size_t ws_size,
                              hipStream_t stream) {
    const float* x   = (const float*)d_in[0];
    const int*   ei  = (const int*)  d_in[1];
    const float* ew  = (const float*)d_in[2];
    const int*   bat = (const int*)  d_in[3];
    const float* W1  = (const float*)d_in[4];
    const float* b1  = (const float*)d_in[5];
    const float* W2  = (const float*)d_in[6];
    const float* b2  = (const float*)d_in[7];
    float* out = (float*)d_out;

    char* ws = (char*)d_ws;
    size_t off = 0;
    float* A      = (float*)(ws + off); off += (size_t)NN * DD * 4;   // 12.8 MB
    float* B      = (float*)(ws + off); off += (size_t)NN * DD * 4;   // 12.8 MB
    int2*  srt    = (int2*) (ws + off); off += (size_t)NE * 8;        // 6.4 MB
    float* dis    = (float*)(ws + off); off += (size_t)NN * 4;
    int*   cnt    = (int*)  (ws + off); off += (size_t)NN * 4;
    int*   rowptr = (int*)  (ws + off); off += (size_t)(NN + 1) * 4;
    int*   pos    = (int*)  (ws + off); off += (size_t)NN * 4;
    float* sums   = (float*)(ws + off); off += (size_t)NG * DD * 4;
    float* cnts   = (float*)(ws + off); off += (size_t)NG * 4;

    // normalization + CSR build (shared by both layers)
    init_k<<<(NN + 255) / 256, 256, 0, stream>>>(dis, cnt, sums, cnts);
    hist_deg<<<(NE + 255) / 256, 256, 0, stream>>>(ei, ew, dis, cnt, NE);
    make_dis<<<(NN + 255) / 256, 256, 0, stream>>>(dis, NN);
    scan_k<<<1, 1024, 0, stream>>>(cnt, rowptr, pos);
    place_k<<<(NE + 255) / 256, 256, 0, stream>>>(ei, ew, dis, pos, srt, NE);

    // layer 1
    gemm_k<false><<<NN / 16, 256, 0, stream>>>(x, W1, nullptr, A);
    gather_k<<<(NN + 3) / 4, 256, 0, stream>>>(rowptr, srt, dis, A, B);

    // layer 2
    gemm_k<true><<<NN / 16, 256, 0, stream>>>(B, W2, b1, A);
    gather_k<<<(NN + 3) / 4, 256, 0, stream>>>(rowptr, srt, dis, A, B);

    // pooling (bias+relu fused on read)
    pool<<<(NN + 127) / 128, 64, 0, stream>>>(B, b2, bat, sums, cnts, NN);
    finalize<<<(NG * DD + 255) / 256, 256, 0, stream>>>(sums, cnts, out);
}

// Round 3
// 331.439 us; speedup vs baseline: 1.5156x; 1.3435x over previous
//
#include <hip/hip_runtime.h>

#define NN 50000
#define NE 800000
#define DD 64
#define NG 64

#define SCAN_TILE 1024                      // 256 threads * 4 elem
#define SCAN_NBLK ((NN + SCAN_TILE - 1) / SCAN_TILE)  // 49

// ---------------- init: deg=1 (self loop), counters = 0 ----------------
__global__ void init_k(float* __restrict__ deg, int* __restrict__ cnt,
                       float* __restrict__ sums, float* __restrict__ cnts) {
    int i = blockIdx.x * blockDim.x + threadIdx.x;
    if (i < NN) { deg[i] = 1.0f; cnt[i] = 0; }
    if (i < NG * DD) sums[i] = 0.0f;
    if (i < NG) cnts[i] = 0.0f;
}

// ---------------- histogram by dst + weighted degree ----------------
__global__ void hist_deg(const int* __restrict__ ei, const float* __restrict__ ew,
                         float* __restrict__ deg, int* __restrict__ cnt, int E) {
    int e = blockIdx.x * blockDim.x + threadIdx.x;
    if (e < E) {
        int c = ei[E + e];
        atomicAdd(&cnt[c], 1);
        unsafeAtomicAdd(&deg[c], ew[e]);
    }
}

__global__ void make_dis(float* __restrict__ deg, int n) {
    int i = blockIdx.x * blockDim.x + threadIdx.x;
    if (i < n) {
        float d = deg[i];
        deg[i] = d > 0.0f ? rsqrtf(d) : 0.0f;  // in-place: deg -> dis
    }
}

// ---------------- 3-phase exclusive scan of cnt ----------------
// phase 1: per-block scan -> relative prefix in rowptr, block totals
__global__ __launch_bounds__(256) void scan1_k(const int* __restrict__ cnt,
                                               int* __restrict__ rowptr,
                                               int* __restrict__ blocksum) {
    __shared__ int wsum[4];
    const int t = threadIdx.x;
    const int base = blockIdx.x * SCAN_TILE + t * 4;
    int v[4], s = 0;
    #pragma unroll
    for (int i = 0; i < 4; ++i) {
        int idx = base + i;
        v[i] = (idx < NN) ? cnt[idx] : 0;
        s += v[i];
    }
    const int lane = t & 63, w = t >> 6;
    int pre = s;  // inclusive wave scan
    #pragma unroll
    for (int off = 1; off < 64; off <<= 1) {
        int u = __shfl_up(pre, off);
        if (lane >= off) pre += u;
    }
    if (lane == 63) wsum[w] = pre;
    __syncthreads();
    int woff = 0;
    for (int i = 0; i < w; ++i) woff += wsum[i];
    int run = woff + pre - s;  // exclusive prefix within block
    #pragma unroll
    for (int i = 0; i < 4; ++i) {
        int idx = base + i;
        if (idx < NN) rowptr[idx] = run;
        run += v[i];
    }
    if (t == 255) blocksum[blockIdx.x] = woff + pre;
}

// phase 2: exclusive scan of SCAN_NBLK block sums (one wave)
__global__ __launch_bounds__(64) void scan2_k(int* __restrict__ blocksum) {
    const int t = threadIdx.x;
    int v = (t < SCAN_NBLK) ? blocksum[t] : 0;
    int pre = v;
    #pragma unroll
    for (int off = 1; off < 64; off <<= 1) {
        int u = __shfl_up(pre, off);
        if (t >= off) pre += u;
    }
    if (t < SCAN_NBLK) blocksum[t] = pre - v;
}

// phase 3: add block offsets, produce final rowptr & pos
__global__ __launch_bounds__(256) void scan3_k(int* __restrict__ rowptr,
                                               const int* __restrict__ blocksum,
                                               int* __restrict__ pos) {
    int i = blockIdx.x * blockDim.x + threadIdx.x;
    if (i < NN) {
        int v = rowptr[i] + blocksum[i / SCAN_TILE];
        rowptr[i] = v;
        pos[i] = v;
    }
    if (i == 0) rowptr[NN] = NE;
}

// ---------------- place edges sorted by dst, with precomputed norm ----------------
__global__ void place_k(const int* __restrict__ ei, const float* __restrict__ ew,
                        const float* __restrict__ dis, int* __restrict__ pos,
                        int2* __restrict__ srt, int E) {
    int e = blockIdx.x * blockDim.x + threadIdx.x;
    if (e < E) {
        int r = ei[e], c = ei[E + e];
        float w = dis[r] * ew[e] * dis[c];
        int p = atomicAdd(&pos[c], 1);
        srt[p] = make_int2(r, __float_as_int(w));
    }
}

// ---------------- GEMM: A = act(X) @ W ----------------
template<bool ACT>
__global__ __launch_bounds__(256) void gemm_k(
    const float* __restrict__ X, const float* __restrict__ W,
    const float* __restrict__ bias_prev, float* __restrict__ A)
{
    __shared__ float Ws[64][64];
    __shared__ float Xs[16][64];
    const int t = threadIdx.x;
    const int row0 = blockIdx.x * 16;

    #pragma unroll
    for (int s = t; s < 64 * 64; s += 256) Ws[s >> 6][s & 63] = W[s];
    #pragma unroll
    for (int s = t; s < 16 * 64; s += 256) {
        int rr = s >> 6, k = s & 63;
        float v = X[(size_t)(row0 + rr) * DD + k];
        if (ACT) v = fmaxf(v + bias_prev[k], 0.0f);
        Xs[rr][k] = v;
    }
    __syncthreads();

    const int j = t & 63;
    const int r0 = t >> 6;
    #pragma unroll
    for (int rr = r0; rr < 16; rr += 4) {
        float acc = 0.0f;
        #pragma unroll
        for (int k = 0; k < 64; ++k) acc += Xs[rr][k] * Ws[k][j];
        A[(size_t)(row0 + rr) * DD + j] = acc;
    }
}

// ---------------- gather: B[c] = A[c]*dis[c]^2 + sum_e A[r]*norm ----------------
__global__ __launch_bounds__(256) void gather_k(
    const int* __restrict__ rowptr, const int2* __restrict__ srt,
    const float* __restrict__ dis,
    const float* __restrict__ A, float* __restrict__ B)
{
    const int node = blockIdx.x * 4 + (threadIdx.x >> 6);
    const int lane = threadIdx.x & 63;
    if (node >= NN) return;
    const float di = dis[node];
    float acc = A[(size_t)node * DD + lane] * di * di;
    int e = rowptr[node];
    const int end = rowptr[node + 1];
    for (; e + 1 < end; e += 2) {
        int2 p0 = srt[e], p1 = srt[e + 1];
        float a0 = A[(size_t)p0.x * DD + lane];
        float a1 = A[(size_t)p1.x * DD + lane];
        acc += a0 * __int_as_float(p0.y);
        acc += a1 * __int_as_float(p1.y);
    }
    if (e < end) {
        int2 p0 = srt[e];
        acc += A[(size_t)p0.x * DD + lane] * __int_as_float(p0.y);
    }
    B[(size_t)node * DD + lane] = acc;
}

// ---------------- pooling ----------------
__global__ __launch_bounds__(64) void pool(
    const float* __restrict__ B, const float* __restrict__ b2,
    const int* __restrict__ batch,
    float* __restrict__ sums, float* __restrict__ cnts, int n)
{
    const int lane = threadIdx.x;
    const int start = blockIdx.x * 128;
    const int end = min(start + 128, n);
    const float bb = b2[lane];
    float acc = 0.0f;
    int cn = 0;
    int curg = batch[start];
    for (int i = start; i < end; ++i) {
        int g = batch[i];
        if (g != curg) {
            unsafeAtomicAdd(&sums[curg * DD + lane], acc);
            if (lane == 0) unsafeAtomicAdd(&cnts[curg], (float)cn);
            acc = 0.0f; cn = 0; curg = g;
        }
        acc += fmaxf(B[(size_t)i * DD + lane] + bb, 0.0f);
        cn++;
    }
    if (cn > 0) {
        unsafeAtomicAdd(&sums[curg * DD + lane], acc);
        if (lane == 0) unsafeAtomicAdd(&cnts[curg], (float)cn);
    }
}

__global__ void finalize(const float* __restrict__ sums, const float* __restrict__ cnts,
                         float* __restrict__ out) {
    int i = blockIdx.x * blockDim.x + threadIdx.x;
    if (i < NG * DD) {
        int g = i >> 6;
        out[i] = sums[i] / fmaxf(cnts[g], 1.0f);
    }
}

// ---------------- host ----------------
extern "C" void kernel_launch(void* const* d_in, const int* in_sizes, int n_in,
                              void* d_out, int out_size, void* d_ws, size_t ws_size,
                              hipStream_t stream) {
    const float* x   = (const float*)d_in[0];
    const int*   ei  = (const int*)  d_in[1];
    const float* ew  = (const float*)d_in[2];
    const int*   bat = (const int*)  d_in[3];
    const float* W1  = (const float*)d_in[4];
    const float* b1  = (const float*)d_in[5];
    const float* W2  = (const float*)d_in[6];
    const float* b2  = (const float*)d_in[7];
    float* out = (float*)d_out;

    char* ws = (char*)d_ws;
    size_t off = 0;
    float* A        = (float*)(ws + off); off += (size_t)NN * DD * 4;   // 12.8 MB
    float* B        = (float*)(ws + off); off += (size_t)NN * DD * 4;   // 12.8 MB
    int2*  srt      = (int2*) (ws + off); off += (size_t)NE * 8;        // 6.4 MB
    float* dis      = (float*)(ws + off); off += (size_t)NN * 4;
    int*   cnt      = (int*)  (ws + off); off += (size_t)NN * 4;
    int*   rowptr   = (int*)  (ws + off); off += (size_t)(NN + 1) * 4;
    int*   pos      = (int*)  (ws + off); off += (size_t)NN * 4;
    int*   blocksum = (int*)  (ws + off); off += (size_t)64 * 4;
    float* sums     = (float*)(ws + off); off += (size_t)NG * DD * 4;
    float* cnts     = (float*)(ws + off); off += (size_t)NG * 4;

    // normalization + CSR build (shared by both layers)
    init_k<<<(NN + 255) / 256, 256, 0, stream>>>(dis, cnt, sums, cnts);
    hist_deg<<<(NE + 255) / 256, 256, 0, stream>>>(ei, ew, dis, cnt, NE);
    make_dis<<<(NN + 255) / 256, 256, 0, stream>>>(dis, NN);
    scan1_k<<<SCAN_NBLK, 256, 0, stream>>>(cnt, rowptr, blocksum);
    scan2_k<<<1, 64, 0, stream>>>(blocksum);
    scan3_k<<<(NN + 255) / 256, 256, 0, stream>>>(rowptr, blocksum, pos);
    place_k<<<(NE + 255) / 256, 256, 0, stream>>>(ei, ew, dis, pos, srt, NE);

    // layer 1
    gemm_k<false><<<NN / 16, 256, 0, stream>>>(x, W1, nullptr, A);
    gather_k<<<(NN + 3) / 4, 256, 0, stream>>>(rowptr, srt, dis, A, B);

    // layer 2
    gemm_k<true><<<NN / 16, 256, 0, stream>>>(B, W2, b1, A);
    gather_k<<<(NN + 3) / 4, 256, 0, stream>>>(rowptr, srt, dis, A, B);

    // pooling (bias+relu fused on read)
    pool<<<(NN + 127) / 128, 64, 0, stream>>>(B, b2, bat, sums, cnts, NN);
    finalize<<<(NG * DD + 255) / 256, 256, 0, stream>>>(sums, cnts, out);
}

// Round 4
// 265.613 us; speedup vs baseline: 1.8912x; 1.2478x over previous
//
#include <hip/hip_runtime.h>
#include <hip/hip_fp16.h>

#define NN 50000
#define NE 800000
#define DD 64
#define NG 64

#define SCAN_TILE 1024                      // 256 threads * 4 elem
#define SCAN_NBLK ((NN + SCAN_TILE - 1) / SCAN_TILE)  // 49

#define Q28 268435456.0f        // 2^28
#define INV_Q28 3.725290298461914e-9f

// ---------------- init: zero packed counters + pool accumulators ----------------
__global__ void init_k(unsigned long long* __restrict__ cnt64,
                       float* __restrict__ sums, float* __restrict__ cnts) {
    int i = blockIdx.x * blockDim.x + threadIdx.x;
    if (i < NN) cnt64[i] = 0ull;
    if (i < NG * DD) sums[i] = 0.0f;
    if (i < NG) cnts[i] = 0.0f;
}

// ---------------- single packed atomic per edge: cnt<<44 | Q28(w) ----------------
__global__ void hist_pack(const int* __restrict__ ei, const float* __restrict__ ew,
                          unsigned long long* __restrict__ cnt64, int E) {
    int e = blockIdx.x * blockDim.x + threadIdx.x;
    if (e < E) {
        int c = ei[E + e];
        unsigned long long contrib =
            (1ull << 44) | (unsigned long long)(unsigned int)(ew[e] * Q28 + 0.5f);
        atomicAdd(&cnt64[c], contrib);
    }
}

// ---------------- scan phase 1: decode cnt64 -> dis, per-block scan ----------------
__global__ __launch_bounds__(256) void scan1_k(const unsigned long long* __restrict__ cnt64,
                                               int* __restrict__ rowptr,
                                               int* __restrict__ blocksum,
                                               float* __restrict__ dis) {
    __shared__ int wsum[4];
    const int t = threadIdx.x;
    const int base = blockIdx.x * SCAN_TILE + t * 4;
    int v[4], s = 0;
    #pragma unroll
    for (int i = 0; i < 4; ++i) {
        int idx = base + i;
        if (idx < NN) {
            unsigned long long p = cnt64[idx];
            v[i] = (int)(p >> 44);
            float deg = 1.0f + (float)(p & ((1ull << 44) - 1)) * INV_Q28;  // self-loop +1
            dis[idx] = rsqrtf(deg);
        } else v[i] = 0;
        s += v[i];
    }
    const int lane = t & 63, w = t >> 6;
    int pre = s;  // inclusive wave scan
    #pragma unroll
    for (int off = 1; off < 64; off <<= 1) {
        int u = __shfl_up(pre, off);
        if (lane >= off) pre += u;
    }
    if (lane == 63) wsum[w] = pre;
    __syncthreads();
    int woff = 0;
    for (int i = 0; i < w; ++i) woff += wsum[i];
    int run = woff + pre - s;  // exclusive prefix within block
    #pragma unroll
    for (int i = 0; i < 4; ++i) {
        int idx = base + i;
        if (idx < NN) rowptr[idx] = run;
        run += v[i];
    }
    if (t == 255) blocksum[blockIdx.x] = woff + pre;
}

// phase 2: exclusive scan of block sums (one wave)
__global__ __launch_bounds__(64) void scan2_k(int* __restrict__ blocksum) {
    const int t = threadIdx.x;
    int v = (t < SCAN_NBLK) ? blocksum[t] : 0;
    int pre = v;
    #pragma unroll
    for (int off = 1; off < 64; off <<= 1) {
        int u = __shfl_up(pre, off);
        if (t >= off) pre += u;
    }
    if (t < SCAN_NBLK) blocksum[t] = pre - v;
}

// phase 3: add block offsets, produce final rowptr & pos
__global__ __launch_bounds__(256) void scan3_k(int* __restrict__ rowptr,
                                               const int* __restrict__ blocksum,
                                               int* __restrict__ pos) {
    int i = blockIdx.x * blockDim.x + threadIdx.x;
    if (i < NN) {
        int v = rowptr[i] + blocksum[i / SCAN_TILE];
        rowptr[i] = v;
        pos[i] = v;
    }
    if (i == 0) rowptr[NN] = NE;
}

// ---------------- place edges sorted by dst: packed (fp16 w | u16 r) ----------------
__global__ void place_k(const int* __restrict__ ei, const float* __restrict__ ew,
                        int* __restrict__ pos, unsigned int* __restrict__ srt, int E) {
    int e = blockIdx.x * blockDim.x + threadIdx.x;
    if (e < E) {
        int r = ei[e], c = ei[E + e];
        unsigned int hb = (unsigned int)__half_as_ushort(__float2half(ew[e]));
        unsigned int packed = (hb << 16) | (unsigned int)r;  // NN < 65536
        int p = atomicAdd(&pos[c], 1);
        srt[p] = packed;
    }
}

// ---------------- GEMM: A' = (act(X) @ W) * dis[row], fp16 out ----------------
template<bool ACT>
__global__ __launch_bounds__(256) void gemm_k(
    const float* __restrict__ X, const float* __restrict__ W,
    const float* __restrict__ bias_prev, const float* __restrict__ dis,
    __half* __restrict__ Ah)
{
    __shared__ float Ws[64][64];
    __shared__ float Xs[16][64];
    const int t = threadIdx.x;
    const int row0 = blockIdx.x * 16;

    #pragma unroll
    for (int s = t; s < 64 * 64; s += 256) Ws[s >> 6][s & 63] = W[s];
    #pragma unroll
    for (int s = t; s < 16 * 64; s += 256) {
        int rr = s >> 6, k = s & 63;
        float v = X[(size_t)(row0 + rr) * DD + k];
        if (ACT) v = fmaxf(v + bias_prev[k], 0.0f);
        Xs[rr][k] = v;
    }
    __syncthreads();

    const int j = t & 63;
    const int r0 = t >> 6;
    #pragma unroll
    for (int rr = r0; rr < 16; rr += 4) {
        float acc = 0.0f;
        #pragma unroll
        for (int k = 0; k < 64; ++k) acc += Xs[rr][k] * Ws[k][j];
        int gi = row0 + rr;
        Ah[(size_t)gi * DD + j] = __float2half(acc * dis[gi]);
    }
}

// ---------------- gather: B[c] = dis[c] * (A'[c] + sum_e w_e * A'[r_e]) ----------------
__global__ __launch_bounds__(256) void gather_k(
    const int* __restrict__ rowptr, const unsigned int* __restrict__ srt,
    const float* __restrict__ dis,
    const __half* __restrict__ Ah, float* __restrict__ B)
{
    const int node = blockIdx.x * 4 + (threadIdx.x >> 6);
    const int lane = threadIdx.x & 63;
    if (node >= NN) return;
    float acc0 = __half2float(Ah[(size_t)node * DD + lane]);  // self-loop term
    float acc1 = 0.0f;
    int e = rowptr[node];
    const int end = rowptr[node + 1];
    for (; e + 3 < end; e += 4) {
        unsigned int u0 = srt[e], u1 = srt[e + 1], u2 = srt[e + 2], u3 = srt[e + 3];
        float a0 = __half2float(Ah[(size_t)(u0 & 0xffffu) * DD + lane]);
        float a1 = __half2float(Ah[(size_t)(u1 & 0xffffu) * DD + lane]);
        float a2 = __half2float(Ah[(size_t)(u2 & 0xffffu) * DD + lane]);
        float a3 = __half2float(Ah[(size_t)(u3 & 0xffffu) * DD + lane]);
        acc0 += a0 * __half2float(__ushort_as_half((unsigned short)(u0 >> 16)));
        acc1 += a1 * __half2float(__ushort_as_half((unsigned short)(u1 >> 16)));
        acc0 += a2 * __half2float(__ushort_as_half((unsigned short)(u2 >> 16)));
        acc1 += a3 * __half2float(__ushort_as_half((unsigned short)(u3 >> 16)));
    }
    for (; e < end; ++e) {
        unsigned int u0 = srt[e];
        float a0 = __half2float(Ah[(size_t)(u0 & 0xffffu) * DD + lane]);
        acc0 += a0 * __half2float(__ushort_as_half((unsigned short)(u0 >> 16)));
    }
    B[(size_t)node * DD + lane] = dis[node] * (acc0 + acc1);
}

// ---------------- pooling ----------------
__global__ __launch_bounds__(64) void pool(
    const float* __restrict__ B, const float* __restrict__ b2,
    const int* __restrict__ batch,
    float* __restrict__ sums, float* __restrict__ cnts, int n)
{
    const int lane = threadIdx.x;
    const int start = blockIdx.x * 128;
    const int end = min(start + 128, n);
    const float bb = b2[lane];
    float acc = 0.0f;
    int cn = 0;
    int curg = batch[start];
    for (int i = start; i < end; ++i) {
        int g = batch[i];
        if (g != curg) {
            unsafeAtomicAdd(&sums[curg * DD + lane], acc);
            if (lane == 0) unsafeAtomicAdd(&cnts[curg], (float)cn);
            acc = 0.0f; cn = 0; curg = g;
        }
        acc += fmaxf(B[(size_t)i * DD + lane] + bb, 0.0f);
        cn++;
    }
    if (cn > 0) {
        unsafeAtomicAdd(&sums[curg * DD + lane], acc);
        if (lane == 0) unsafeAtomicAdd(&cnts[curg], (float)cn);
    }
}

__global__ void finalize(const float* __restrict__ sums, const float* __restrict__ cnts,
                         float* __restrict__ out) {
    int i = blockIdx.x * blockDim.x + threadIdx.x;
    if (i < NG * DD) {
        int g = i >> 6;
        out[i] = sums[i] / fmaxf(cnts[g], 1.0f);
    }
}

// ---------------- host ----------------
extern "C" void kernel_launch(void* const* d_in, const int* in_sizes, int n_in,
                              void* d_out, int out_size, void* d_ws, size_t ws_size,
                              hipStream_t stream) {
    const float* x   = (const float*)d_in[0];
    const int*   ei  = (const int*)  d_in[1];
    const float* ew  = (const float*)d_in[2];
    const int*   bat = (const int*)  d_in[3];
    const float* W1  = (const float*)d_in[4];
    const float* b1  = (const float*)d_in[5];
    const float* W2  = (const float*)d_in[6];
    const float* b2  = (const float*)d_in[7];
    float* out = (float*)d_out;

    char* ws = (char*)d_ws;
    size_t off = 0;
    __half* Ah      = (__half*)(ws + off); off += (size_t)NN * DD * 2;   // 6.4 MB
    float*  B       = (float*) (ws + off); off += (size_t)NN * DD * 4;   // 12.8 MB
    unsigned int* srt = (unsigned int*)(ws + off); off += (size_t)NE * 4; // 3.2 MB
    unsigned long long* cnt64 = (unsigned long long*)(ws + off); off += (size_t)NN * 8;
    float*  dis     = (float*) (ws + off); off += (size_t)NN * 4;
    int*    rowptr  = (int*)   (ws + off); off += (size_t)(NN + 1) * 4;
    int*    pos     = (int*)   (ws + off); off += (size_t)NN * 4;
    int*    blocksum= (int*)   (ws + off); off += (size_t)64 * 4;
    float*  sums    = (float*) (ws + off); off += (size_t)NG * DD * 4;
    float*  cnts    = (float*) (ws + off); off += (size_t)NG * 4;

    // CSR + normalization build (shared by both layers)
    init_k<<<(NN + 255) / 256, 256, 0, stream>>>(cnt64, sums, cnts);
    hist_pack<<<(NE + 255) / 256, 256, 0, stream>>>(ei, ew, cnt64, NE);
    scan1_k<<<SCAN_NBLK, 256, 0, stream>>>(cnt64, rowptr, blocksum, dis);
    scan2_k<<<1, 64, 0, stream>>>(blocksum);
    scan3_k<<<(NN + 255) / 256, 256, 0, stream>>>(rowptr, blocksum, pos);
    place_k<<<(NE + 255) / 256, 256, 0, stream>>>(ei, ew, pos, srt, NE);

    // layer 1
    gemm_k<false><<<NN / 16, 256, 0, stream>>>(x, W1, nullptr, dis, Ah);
    gather_k<<<(NN + 3) / 4, 256, 0, stream>>>(rowptr, srt, dis, Ah, B);

    // layer 2
    gemm_k<true><<<NN / 16, 256, 0, stream>>>(B, W2, b1, dis, Ah);
    gather_k<<<(NN + 3) / 4, 256, 0, stream>>>(rowptr, srt, dis, Ah, B);

    // pooling (bias+relu fused on read)
    pool<<<(NN + 127) / 128, 64, 0, stream>>>(B, b2, bat, sums, cnts, NN);
    finalize<<<(NG * DD + 255) / 256, 256, 0, stream>>>(sums, cnts, out);
}

// Round 5
// 202.068 us; speedup vs baseline: 2.4859x; 1.3145x over previous
//
#include <hip/hip_runtime.h>
#include <hip/hip_fp16.h>

#define NN 50000
#define NE 800000
#define DD 64
#define NG 64

#define NBKT 196        // ceil(NN/256) coarse buckets (dst >> 8)
#define MAXB 5120       // padded tmp slots per bucket (mean 4082, sigma ~64)
#define P1CH 4096       // edges per pass-1 block
#define P1NB ((NE + P1CH - 1) / P1CH)   // 196

// ---------------- init: bucket bases + pool accumulators ----------------
__global__ void init_k(int* __restrict__ bucket_pos,
                       float* __restrict__ sums, float* __restrict__ cnts) {
    int i = blockIdx.x * blockDim.x + threadIdx.x;
    if (i < NBKT) bucket_pos[i] = i * MAXB;
    if (i < NG * DD) sums[i] = 0.0f;
    if (i < NG) cnts[i] = 0.0f;
}

// ---------------- pass 1: bin edges by dst>>8 into padded tmp buckets ----------------
__global__ __launch_bounds__(256) void bin_k(const int* __restrict__ ei,
                                             const float* __restrict__ ew,
                                             int* __restrict__ bucket_pos,
                                             unsigned int* __restrict__ tmp_pay,
                                             unsigned char* __restrict__ tmp_c8) {
    __shared__ int hist[NBKT];
    __shared__ int basec[NBKT];
    const int t = threadIdx.x;
    const int e0 = blockIdx.x * P1CH;
    for (int i = t; i < NBKT; i += 256) hist[i] = 0;
    __syncthreads();
    int rr[16]; int cc[16]; float wwf[16];
    #pragma unroll
    for (int i = 0; i < 16; ++i) {
        int e = e0 + i * 256 + t;
        if (e < NE) {
            rr[i] = ei[e]; cc[i] = ei[NE + e]; wwf[i] = ew[e];
            atomicAdd(&hist[cc[i] >> 8], 1);
        } else cc[i] = -1;
    }
    __syncthreads();
    // one global atomic per (block, bucket): reserve contiguous region
    for (int i = t; i < NBKT; i += 256) basec[i] = atomicAdd(&bucket_pos[i], hist[i]);
    __syncthreads();
    #pragma unroll
    for (int i = 0; i < 16; ++i) {
        if (cc[i] >= 0) {
            int b = cc[i] >> 8;
            int slot = atomicAdd(&basec[b], 1);   // LDS cursor within reservation
            unsigned int hb = (unsigned int)__half_as_ushort(__float2half(wwf[i]));
            tmp_pay[slot] = (hb << 16) | (unsigned int)rr[i];
            tmp_c8[slot] = (unsigned char)(cc[i] & 255);
        }
    }
}

// ---------------- scan of bucket counts -> global bucket bases ----------------
__global__ __launch_bounds__(256) void bscan_k(const int* __restrict__ bucket_pos,
                                               int* __restrict__ gbase,
                                               int* __restrict__ rowptr) {
    __shared__ int wtot[4];
    const int t = threadIdx.x;
    int v = (t < NBKT) ? (bucket_pos[t] - t * MAXB) : 0;
    int pre = v;
    #pragma unroll
    for (int off = 1; off < 64; off <<= 1) {
        int u = __shfl_up(pre, off);
        if ((t & 63) >= off) pre += u;
    }
    if ((t & 63) == 63) wtot[t >> 6] = pre;
    __syncthreads();
    int woff = 0;
    for (int i = 0; i < (t >> 6); ++i) woff += wtot[i];
    if (t < NBKT) gbase[t] = woff + pre - v;
    if (t == 0) rowptr[NN] = NE;
}

// ---------------- pass 2: per-bucket exact sort + rowptr + dis ----------------
__global__ __launch_bounds__(256) void build_k(const int* __restrict__ bucket_pos,
                                               const int* __restrict__ gbase,
                                               const unsigned int* __restrict__ tmp_pay,
                                               const unsigned char* __restrict__ tmp_c8,
                                               unsigned int* __restrict__ srt,
                                               int* __restrict__ rowptr,
                                               float* __restrict__ dis) {
    __shared__ int hist[256];
    __shared__ int cursor[256];
    __shared__ float degf[256];
    __shared__ int wtot[4];
    const int b = blockIdx.x;
    const int t = threadIdx.x;
    const int cntb = bucket_pos[b] - b * MAXB;
    const int tbase = b * MAXB;
    hist[t] = 0; degf[t] = 0.0f;
    __syncthreads();
    for (int i = t; i < cntb; i += 256) atomicAdd(&hist[tmp_c8[tbase + i]], 1);
    __syncthreads();
    // exclusive scan of hist (256 values, 4 waves)
    int v = hist[t];
    int pre = v;
    #pragma unroll
    for (int off = 1; off < 64; off <<= 1) {
        int u = __shfl_up(pre, off);
        if ((t & 63) >= off) pre += u;
    }
    if ((t & 63) == 63) wtot[t >> 6] = pre;
    __syncthreads();
    int woff = 0;
    for (int i = 0; i < (t >> 6); ++i) woff += wtot[i];
    const int excl = gbase[b] + woff + pre - v;
    const int node = b * 256 + t;
    if (node < NN) rowptr[node] = excl;
    cursor[t] = excl;
    __syncthreads();
    for (int i = t; i < cntb; i += 256) {
        unsigned int u = tmp_pay[tbase + i];
        int c8 = tmp_c8[tbase + i];
        int slot = atomicAdd(&cursor[c8], 1);   // LDS
        srt[slot] = u;
        float w = __half2float(__ushort_as_half((unsigned short)(u >> 16)));
        atomicAdd(&degf[c8], w);                // LDS fp32
    }
    __syncthreads();
    if (node < NN) dis[node] = rsqrtf(1.0f + degf[t]);
}

// ---------------- GEMM: A' = (act(X) @ W) * dis[row], fp16 out ----------------
template<bool ACT>
__global__ __launch_bounds__(256) void gemm_k(
    const float* __restrict__ X, const float* __restrict__ W,
    const float* __restrict__ bias_prev, const float* __restrict__ dis,
    __half* __restrict__ Ah)
{
    __shared__ float Ws[64][64];
    __shared__ float Xs[16][64];
    const int t = threadIdx.x;
    const int row0 = blockIdx.x * 16;

    #pragma unroll
    for (int s = t; s < 64 * 64; s += 256) Ws[s >> 6][s & 63] = W[s];
    #pragma unroll
    for (int s = t; s < 16 * 64; s += 256) {
        int rr = s >> 6, k = s & 63;
        float v = X[(size_t)(row0 + rr) * DD + k];
        if (ACT) v = fmaxf(v + bias_prev[k], 0.0f);
        Xs[rr][k] = v;
    }
    __syncthreads();

    const int j = t & 63;
    const int r0 = t >> 6;
    #pragma unroll
    for (int rr = r0; rr < 16; rr += 4) {
        float acc = 0.0f;
        #pragma unroll
        for (int k = 0; k < 64; ++k) acc += Xs[rr][k] * Ws[k][j];
        int gi = row0 + rr;
        Ah[(size_t)gi * DD + j] = __float2half(acc * dis[gi]);
    }
}

// ---------------- gather: B[c] = dis[c] * (A'[c] + sum_e w_e * A'[r_e]) ----------------
__global__ __launch_bounds__(256) void gather_k(
    const int* __restrict__ rowptr, const unsigned int* __restrict__ srt,
    const float* __restrict__ dis,
    const __half* __restrict__ Ah, float* __restrict__ B)
{
    const int node = blockIdx.x * 4 + (threadIdx.x >> 6);
    const int lane = threadIdx.x & 63;
    if (node >= NN) return;
    float acc0 = __half2float(Ah[(size_t)node * DD + lane]);  // self-loop term
    float acc1 = 0.0f;
    int e = rowptr[node];
    const int end = rowptr[node + 1];
    for (; e + 3 < end; e += 4) {
        unsigned int u0 = srt[e], u1 = srt[e + 1], u2 = srt[e + 2], u3 = srt[e + 3];
        float a0 = __half2float(Ah[(size_t)(u0 & 0xffffu) * DD + lane]);
        float a1 = __half2float(Ah[(size_t)(u1 & 0xffffu) * DD + lane]);
        float a2 = __half2float(Ah[(size_t)(u2 & 0xffffu) * DD + lane]);
        float a3 = __half2float(Ah[(size_t)(u3 & 0xffffu) * DD + lane]);
        acc0 += a0 * __half2float(__ushort_as_half((unsigned short)(u0 >> 16)));
        acc1 += a1 * __half2float(__ushort_as_half((unsigned short)(u1 >> 16)));
        acc0 += a2 * __half2float(__ushort_as_half((unsigned short)(u2 >> 16)));
        acc1 += a3 * __half2float(__ushort_as_half((unsigned short)(u3 >> 16)));
    }
    for (; e < end; ++e) {
        unsigned int u0 = srt[e];
        float a0 = __half2float(Ah[(size_t)(u0 & 0xffffu) * DD + lane]);
        acc0 += a0 * __half2float(__ushort_as_half((unsigned short)(u0 >> 16)));
    }
    B[(size_t)node * DD + lane] = dis[node] * (acc0 + acc1);
}

// ---------------- pooling ----------------
__global__ __launch_bounds__(64) void pool(
    const float* __restrict__ B, const float* __restrict__ b2,
    const int* __restrict__ batch,
    float* __restrict__ sums, float* __restrict__ cnts, int n)
{
    const int lane = threadIdx.x;
    const int start = blockIdx.x * 128;
    const int end = min(start + 128, n);
    const float bb = b2[lane];
    float acc = 0.0f;
    int cn = 0;
    int curg = batch[start];
    for (int i = start; i < end; ++i) {
        int g = batch[i];
        if (g != curg) {
            unsafeAtomicAdd(&sums[curg * DD + lane], acc);
            if (lane == 0) unsafeAtomicAdd(&cnts[curg], (float)cn);
            acc = 0.0f; cn = 0; curg = g;
        }
        acc += fmaxf(B[(size_t)i * DD + lane] + bb, 0.0f);
        cn++;
    }
    if (cn > 0) {
        unsafeAtomicAdd(&sums[curg * DD + lane], acc);
        if (lane == 0) unsafeAtomicAdd(&cnts[curg], (float)cn);
    }
}

__global__ void finalize(const float* __restrict__ sums, const float* __restrict__ cnts,
                         float* __restrict__ out) {
    int i = blockIdx.x * blockDim.x + threadIdx.x;
    if (i < NG * DD) {
        int g = i >> 6;
        out[i] = sums[i] / fmaxf(cnts[g], 1.0f);
    }
}

// ---------------- host ----------------
extern "C" void kernel_launch(void* const* d_in, const int* in_sizes, int n_in,
                              void* d_out, int out_size, void* d_ws, size_t ws_size,
                              hipStream_t stream) {
    const float* x   = (const float*)d_in[0];
    const int*   ei  = (const int*)  d_in[1];
    const float* ew  = (const float*)d_in[2];
    const int*   bat = (const int*)  d_in[3];
    const float* W1  = (const float*)d_in[4];
    const float* b1  = (const float*)d_in[5];
    const float* W2  = (const float*)d_in[6];
    const float* b2  = (const float*)d_in[7];
    float* out = (float*)d_out;

    char* ws = (char*)d_ws;
    size_t off = 0;
    __half* Ah        = (__half*)(ws + off); off += (size_t)NN * DD * 2;          // 6.4 MB
    float*  B         = (float*) (ws + off); off += (size_t)NN * DD * 4;          // 12.8 MB
    unsigned int* srt = (unsigned int*)(ws + off); off += (size_t)NE * 4;         // 3.2 MB
    unsigned int* tmp_pay = (unsigned int*)(ws + off); off += (size_t)NBKT * MAXB * 4;  // 4.0 MB
    unsigned char* tmp_c8 = (unsigned char*)(ws + off); off += (size_t)NBKT * MAXB;     // 1.0 MB
    int*    bucket_pos = (int*)(ws + off); off += (size_t)NBKT * 4;
    int*    gbase      = (int*)(ws + off); off += (size_t)NBKT * 4;
    int*    rowptr     = (int*)(ws + off); off += (size_t)(NN + 1) * 4;
    float*  dis        = (float*)(ws + off); off += (size_t)NN * 4;
    float*  sums       = (float*)(ws + off); off += (size_t)NG * DD * 4;
    float*  cnts       = (float*)(ws + off); off += (size_t)NG * 4;

    // CSR + normalization build (shared by both layers) — no per-edge global atomics
    init_k<<<(NG * DD + 255) / 256, 256, 0, stream>>>(bucket_pos, sums, cnts);
    bin_k<<<P1NB, 256, 0, stream>>>(ei, ew, bucket_pos, tmp_pay, tmp_c8);
    bscan_k<<<1, 256, 0, stream>>>(bucket_pos, gbase, rowptr);
    build_k<<<NBKT, 256, 0, stream>>>(bucket_pos, gbase, tmp_pay, tmp_c8, srt, rowptr, dis);

    // layer 1
    gemm_k<false><<<NN / 16, 256, 0, stream>>>(x, W1, nullptr, dis, Ah);
    gather_k<<<(NN + 3) / 4, 256, 0, stream>>>(rowptr, srt, dis, Ah, B);

    // layer 2
    gemm_k<true><<<NN / 16, 256, 0, stream>>>(B, W2, b1, dis, Ah);
    gather_k<<<(NN + 3) / 4, 256, 0, stream>>>(rowptr, srt, dis, Ah, B);

    // pooling (bias+relu fused on read)
    pool<<<(NN + 127) / 128, 64, 0, stream>>>(B, b2, bat, sums, cnts, NN);
    finalize<<<(NG * DD + 255) / 256, 256, 0, stream>>>(sums, cnts, out);
}